// Round 11
// baseline (549.350 us; speedup 1.0000x reference)
//
#include <hip/hip_runtime.h>
#include <hip/hip_bf16.h>

#define T_  4
#define B_  32
#define C_  512
#define CV_ 2048
#define N_  256
#define NH_ 8
#define DH_ 64
#define DV_ 256

typedef __bf16 bf16_t;
typedef __bf16 bf16x8 __attribute__((ext_vector_type(8)));
typedef float  f32x4  __attribute__((ext_vector_type(4)));
typedef unsigned char u8x8 __attribute__((ext_vector_type(8)));

#if defined(__has_builtin)
# if __has_builtin(__builtin_amdgcn_global_load_lds)
#  define USE_GLL 1
# endif
#endif

__device__ __forceinline__ f32x4 mfma16(bf16x8 a, bf16x8 b, f32x4 c) {
  return __builtin_amdgcn_mfma_f32_16x16x32_bf16(a, b, c, 0, 0, 0);
}

// s = round(clip(u,0,8)); rintf = round-half-even, matching jnp.round/np.round
__device__ __forceinline__ float quant_step(float u) {
  return rintf(fminf(fmaxf(u, 0.0f), 8.0f));
}

// uchar8 (spike ints 0..8) -> bf16x8 exact integer values
__device__ __forceinline__ bf16x8 cvt8(u8x8 v) {
  bf16x8 r;
#pragma unroll
  for (int j = 0; j < 8; ++j) r[j] = (bf16_t)(float)(unsigned int)v[j];
  return r;
}

// Async 16B/lane global->LDS stage; lbase wave-uniform, HW dest = lbase+lane*16.
__device__ __forceinline__ void stage16(const void* g, void* lbase, int lane) {
#ifdef USE_GLL
  __builtin_amdgcn_global_load_lds(
      (const __attribute__((address_space(1))) void*)g,
      (__attribute__((address_space(3))) void*)lbase, 16, 0, 0);
#else
  *(uint4*)((char*)lbase + lane * 16) = *(const uint4*)g;
#endif
}

// ---------------- Kernel 0: split f32 weights into bf16 hi + lo ----------------
__global__ __launch_bounds__(256) void k0_split(const float* __restrict__ src,
                                                bf16_t* __restrict__ hi,
                                                bf16_t* __restrict__ lo, int n8) {
  int i = blockIdx.x * 256 + threadIdx.x;
  if (i >= n8) return;
  const float* s = src + (size_t)i * 8;
  bf16x8 h, l;
#pragma unroll
  for (int j = 0; j < 8; ++j) {
    float w = s[j];
    __bf16 hh = (__bf16)w;
    h[j] = hh;
    l[j] = (__bf16)(w - (float)hh);   // near-exact residual
  }
  *(bf16x8*)(hi + (size_t)i * 8) = h;
  *(bf16x8*)(lo + (size_t)i * 8) = l;
}

// k0 merged: wq(128 blk) | wk(128 blk) | wv(512 blk) in one 768-block launch.
__global__ __launch_bounds__(256) void k0_split3(
    const float* __restrict__ wq, const float* __restrict__ wk,
    const float* __restrict__ wv, bf16_t* __restrict__ hi,
    bf16_t* __restrict__ lo) {
  int bx = blockIdx.x;
  const float* src; size_t off8; int li;
  if (bx < 128)      { src = wq; off8 = 0;     li = bx; }
  else if (bx < 256) { src = wk; off8 = 32768; li = bx - 128; }
  else               { src = wv; off8 = 65536; li = bx - 256; }
  int i = li * 256 + threadIdx.x;              // exact coverage, no bounds check
  const float* s = src + (size_t)i * 8;
  bf16x8 h, l;
#pragma unroll
  for (int j = 0; j < 8; ++j) {
    float w = s[j];
    __bf16 hh = (__bf16)w;
    h[j] = hh;
    l[j] = (__bf16)(w - (float)hh);
  }
  *(bf16x8*)(hi + (off8 + (size_t)i) * 8) = h;
  *(bf16x8*)(lo + (off8 + (size_t)i) * 8) = l;
}

// ---------------- Kernel 1: xs = sfa(x) -> xsT [t,b,n,c] u8 spike ints ------------
__global__ __launch_bounds__(256) void k1_sfa_x(const float* __restrict__ x,
                                                unsigned char* __restrict__ xsT) {
  __shared__ unsigned char tile[64 * 80];        // [n][c], pad 80
  int bt = blockIdx.x;                            // c-tile = bt>>2, n-tile = bt&3
  int b  = blockIdx.y;
  int tid = threadIdx.x;
  int c0 = (bt >> 2) * 64, n0 = (bt & 3) * 64;
  int cl = tid >> 2, nc = (tid & 3) * 16;        // reader role
  int nl = tid >> 2, cj = (tid & 3) * 16;        // writer role

  float h[16];
#pragma unroll
  for (int j = 0; j < 16; ++j) h[j] = 0.0f;

  for (int t = 0; t < T_; ++t) {
    const float* xp = x + ((size_t)(t * B_ + b) * C_ + c0 + cl) * N_ + n0 + nc;
    f32x4 xv[4];
#pragma unroll
    for (int j = 0; j < 4; ++j) xv[j] = *(const f32x4*)(xp + j * 4);
    if (t) __syncthreads();
#pragma unroll
    for (int j = 0; j < 16; ++j) {
      float u = __fadd_rn(h[j], xv[j >> 2][j & 3]);  // reference scan op order
      float s = quant_step(u);
      h[j] = __fsub_rn(u, s);                    // exact
      tile[(nc + j) * 80 + cl] = (unsigned char)s;
    }
    __syncthreads();
    uint4 o = *(const uint4*)&tile[nl * 80 + cj];
    *(uint4*)(xsT + ((size_t)(t * B_ + b) * N_ + n0 + nl) * C_ + c0 + cj) = o;
  }
}

// ---------------- Kernel 2: q|k|v = sfa(conv_bn(xs, W)) ---------------------------
// R0 body (proven 155 us, pipes sum ~100% at 3 blocks/CU), merged dispatch
// (48x4x32 = 6144 blocks = 8 full scheduling rounds, zero tail). Bit-exact.
template<bool SWAPQ>
__device__ __forceinline__ void k2_body(
    const unsigned char* __restrict__ xsT,
    const bf16_t* __restrict__ w_hi, const bf16_t* __restrict__ w_lo,
    const float* __restrict__ q_scale, const float* __restrict__ q_bias,
    const float* __restrict__ k_scale, const float* __restrict__ k_bias,
    const float* __restrict__ v_scale, const float* __restrict__ v_bias,
    unsigned char* __restrict__ q_s8, unsigned char* __restrict__ k_s8,
    unsigned char* __restrict__ v_s8, int ct, int ntile, int b,
    unsigned char (*xs_l)[4][1024], bf16_t* whi_l, bf16_t* wlo_l) {
  int tid = threadIdx.x;
  int w = tid >> 6, lane = tid & 63, quad = lane >> 4, l16 = lane & 15;

  int mode, co_out;
  const float *scp, *bip;
  if (ct < 8)       { mode = 0; co_out = ct * 64;        scp = q_scale; bip = q_bias; }
  else if (ct < 16) { mode = 1; co_out = (ct - 8) * 64;  scp = k_scale; bip = k_bias; }
  else              { mode = 2; co_out = (ct - 16) * 64; scp = v_scale; bip = v_bias; }

  const bf16_t* wrow = w_hi + (size_t)ct * 64 * C_;
  const bf16_t* lrow = w_lo + (size_t)ct * 64 * C_;
  int n0b = ntile * 64;

  int r4 = lane >> 2, m4 = lane & 3;             // u8 staging roles
  int sw4 = (r4 + (r4 >> 2)) & 3;
  int r8 = lane >> 3, m8 = lane & 7;             // bf16 staging roles

  f32x4 acc[T_][4];                              // [t][mt]
#pragma unroll
  for (int t = 0; t < T_; ++t)
#pragma unroll
    for (int mt = 0; mt < 4; ++mt) acc[t][mt] = (f32x4){0.f, 0.f, 0.f, 0.f};

  for (int kc = 0; kc < 8; ++kc) {               // K = 512, BK = 64
    int c0 = kc * 64;
    __syncthreads();
    // stage xs: one instr per t (wave's own 16 n-rows)
#pragma unroll
    for (int t = 0; t < T_; ++t) {
      const unsigned char* g = xsT +
          ((size_t)(t * B_ + b) * N_ + n0b + w * 16 + r4) * C_ + c0 + ((m4 ^ sw4) << 4);
      stage16(g, &xs_l[t][w][0], lane);
    }
    // stage w hi/lo: 2+2 instr per wave
#pragma unroll
    for (int j = 0; j < 2; ++j) {
      int r0 = w * 16 + j * 8;
      int row = r0 + r8;
      int col = c0 + ((m8 ^ (row & 7)) << 3);
      stage16(wrow + (size_t)row * C_ + col, (char*)whi_l + r0 * 128, lane);
      stage16(lrow + (size_t)row * C_ + col, (char*)wlo_l + r0 * 128, lane);
    }
    __syncthreads();
#pragma unroll
    for (int ks = 0; ks < 2; ++ks) {
      int kb = ks * 4 + quad;                    // 8-elem k-granule 0..7
      int slot = (kb >> 1) ^ ((l16 + (l16 >> 2)) & 3);
      int xoff = l16 * 64 + slot * 16 + (kb & 1) * 8;
      bf16x8 bx[T_];
#pragma unroll
      for (int t = 0; t < T_; ++t)
        bx[t] = cvt8(*(const u8x8*)((const char*)&xs_l[t][w][0] + xoff));
#pragma unroll
      for (int mt = 0; mt < 4; ++mt) {
        int row = mt * 16 + l16;
        int woff = row * 128 + ((kb ^ (row & 7)) << 4);
        bf16x8 ah = *(const bf16x8*)((const char*)whi_l + woff);
        bf16x8 al = *(const bf16x8*)((const char*)wlo_l + woff);
#pragma unroll
        for (int t = 0; t < T_; ++t) {
          if (SWAPQ) {
            acc[t][mt] = mfma16(bx[t], ah, acc[t][mt]);
            acc[t][mt] = mfma16(bx[t], al, acc[t][mt]);
          } else {
            acc[t][mt] = mfma16(ah, bx[t], acc[t][mt]);
            acc[t][mt] = mfma16(al, bx[t], acc[t][mt]);
          }
        }
      }
    }
  }
  // epilogue: affine (no FMA contraction; /8 folded exactly) + t-scan + u8 store
  if (SWAPQ) {
    float sc[4], bi[4], h[4][4];
#pragma unroll
    for (int mt = 0; mt < 4; ++mt) {
      int c = co_out + mt * 16 + l16;
      sc[mt] = __fmul_rn(q_scale[c], 0.125f);    // exact pow2 fold
      bi[mt] = q_bias[c];
#pragma unroll
      for (int r = 0; r < 4; ++r) h[mt][r] = 0.0f;
    }
#pragma unroll
    for (int t = 0; t < T_; ++t)
#pragma unroll
      for (int mt = 0; mt < 4; ++mt)
#pragma unroll
        for (int r = 0; r < 4; ++r) {
          float y = __fmul_rn(acc[t][mt][r], sc[mt]);
          y = __fadd_rn(y, bi[mt]);
          float u = __fadd_rn(h[mt][r], y);
          float s = quant_step(u);
          h[mt][r] = __fsub_rn(u, s);
          int n = n0b + w * 16 + quad * 4 + r;
          int c = co_out + mt * 16 + l16;
          q_s8[((size_t)(t * B_ + b) * N_ + n) * C_ + c] = (unsigned char)s;
        }
  } else {
    float sc[4][4], bi[4][4], h[4][4];
#pragma unroll
    for (int mt = 0; mt < 4; ++mt)
#pragma unroll
      for (int r = 0; r < 4; ++r) {
        int c = co_out + mt * 16 + quad * 4 + r;
        sc[mt][r] = __fmul_rn(scp[c], 0.125f);
        bi[mt][r] = bip[c];
        h[mt][r] = 0.0f;
      }
#pragma unroll
    for (int t = 0; t < T_; ++t)
#pragma unroll
      for (int mt = 0; mt < 4; ++mt)
#pragma unroll
        for (int r = 0; r < 4; ++r) {
          float y = __fmul_rn(acc[t][mt][r], sc[mt][r]);
          y = __fadd_rn(y, bi[mt][r]);
          float u = __fadd_rn(h[mt][r], y);
          float s = quant_step(u);
          h[mt][r] = __fsub_rn(u, s);
          int n = n0b + w * 16 + l16;
          int c = co_out + mt * 16 + quad * 4 + r;
          unsigned char sp = (unsigned char)s;
          if (mode == 1) k_s8[((size_t)(t * B_ + b) * C_ + c) * N_ + n] = sp;
          else           v_s8[((size_t)(t * B_ + b) * CV_ + c) * N_ + n] = sp;
        }
  }
}

__global__ __launch_bounds__(256, 3) void k2_all(
    const unsigned char* __restrict__ xsT,
    const bf16_t* __restrict__ w_hi, const bf16_t* __restrict__ w_lo,
    const float* __restrict__ q_scale, const float* __restrict__ q_bias,
    const float* __restrict__ k_scale, const float* __restrict__ k_bias,
    const float* __restrict__ v_scale, const float* __restrict__ v_bias,
    unsigned char* __restrict__ q_s8, unsigned char* __restrict__ k_s8,
    unsigned char* __restrict__ v_s8) {
  __shared__ __align__(16) unsigned char xs_l[T_][4][1024];  // 16 KB
  __shared__ __align__(16) bf16_t whi_l[64 * 64];            //  8 KB
  __shared__ __align__(16) bf16_t wlo_l[64 * 64];            //  8 KB
  int ct = blockIdx.x, ntile = blockIdx.y, b = blockIdx.z;
  if (ct < 8)
    k2_body<true>(xsT, w_hi, w_lo, q_scale, q_bias, k_scale, k_bias,
                  v_scale, v_bias, q_s8, k_s8, v_s8, ct, ntile, b,
                  xs_l, whi_l, wlo_l);
  else
    k2_body<false>(xsT, w_hi, w_lo, q_scale, q_bias, k_scale, k_bias,
                   v_scale, v_bias, q_s8, k_s8, v_s8, ct, ntile, b,
                   xs_l, whi_l, wlo_l);
}

// ---------------- Kernel 3: attention (q·(k^T v)) + sfa, exact --------------------
// Restructured this round. All intermediates are exact (integers scaled by pow2,
// < 2^24), so reordering is bit-safe:
//  - KV phase: operands SWAPPED -> lane holds kv[e][d] (e-row, d-col).
//  - hi/lo bf16 conversion done ONCE per element at WRITE time (16/lane/t, was 64
//    at read time), stored to [e][d] bf16 arrays with k2's XOR-granule swizzle.
//  - A-phase fragment = 2x ds_read_b128 (was 8x scalar ds_read_b32 + 8 cvt chains).
// Read values bit-identical; A-phase MFMA order unchanged; epilogue unchanged.
__global__ __launch_bounds__(256) void k3_attn(
    const unsigned char* __restrict__ q_s8, const unsigned char* __restrict__ k_s8,
    const unsigned char* __restrict__ v_s8, unsigned char* __restrict__ a_s8) {
  __shared__ __align__(16) bf16_t kvh[64 * 64];  // [e][d] hi, XOR-swizzled, 8 KB
  __shared__ __align__(16) bf16_t kvl[64 * 64];  // [e][d] lo, 8 KB
  int et = blockIdx.x, hh = blockIdx.y, b = blockIdx.z;
  int tid = threadIdx.x;
  int w = tid >> 6, lane = tid & 63, quad = lane >> 4, l16 = lane & 15;
  int e0 = et * 64;

  f32x4 Aacc[4][4];
#pragma unroll
  for (int mt = 0; mt < 4; ++mt)
#pragma unroll
    for (int nt = 0; nt < 4; ++nt) Aacc[mt][nt] = (f32x4){0.f, 0.f, 0.f, 0.f};

  for (int t = 0; t < T_; ++t) {
    size_t tb = (size_t)(t * B_ + b);
    f32x4 kva[4];                                // [et2]: kv[e][d] e=et2*16+quad*4+r
#pragma unroll
    for (int et2 = 0; et2 < 4; ++et2) kva[et2] = (f32x4){0.f, 0.f, 0.f, 0.f};
    const unsigned char* krow  = k_s8 + ((size_t)tb * C_ + hh * DH_ + w * 16 + l16) * N_;
    const unsigned char* vbase = v_s8 + ((size_t)tb * CV_ + hh * DV_ + e0) * N_;
    for (int kc = 0; kc < 8; ++kc) {
      int koff = kc * 32 + quad * 8;
      bf16x8 a = cvt8(*(const u8x8*)(krow + koff));
#pragma unroll
      for (int et2 = 0; et2 < 4; ++et2) {
        bf16x8 bb = cvt8(*(const u8x8*)(vbase + (size_t)(et2 * 16 + l16) * N_ + koff));
        kva[et2] = mfma16(bb, a, kva[et2]);      // SWAPPED: out row=e, col=d (exact)
      }
    }
    __syncthreads();                             // prev t's A-phase reads done
    // hi/lo convert once per element; write [e][d] with XOR-granule swizzle
#pragma unroll
    for (int et2 = 0; et2 < 4; ++et2)
#pragma unroll
      for (int r = 0; r < 4; ++r) {
        int e = et2 * 16 + quad * 4 + r;
        int d = w * 16 + l16;
        float v = kva[et2][r] * 0.015625f;       // exact pow2
        __bf16 hi = (__bf16)v;
        __bf16 lo = (__bf16)(v - (float)hi);     // exact residual (<=14 sig bits)
        int byteoff = e * 128 + ((((d >> 3) ^ (e & 7)) << 4)) + (d & 7) * 2;
        *(bf16_t*)((char*)kvh + byteoff) = hi;
        *(bf16_t*)((char*)kvl + byteoff) = lo;
      }
    __syncthreads();

    const unsigned char* qrow = q_s8 + ((size_t)tb * N_ + w * 64) * C_ + hh * DH_;
    for (int kc2 = 0; kc2 < 2; ++kc2) {
      int kbase = kc2 * 32 + quad * 8;
      bf16x8 bq[4];
#pragma unroll
      for (int nt = 0; nt < 4; ++nt)
        bq[nt] = cvt8(*(const u8x8*)(qrow + (size_t)(nt * 16 + l16) * C_ + kbase));
#pragma unroll
      for (int mt = 0; mt < 4; ++mt) {
        int e = mt * 16 + l16;
        int goff = e * 128 + (((kc2 * 4 + quad) ^ (e & 7)) << 4);
        bf16x8 ahi = *(const bf16x8*)((const char*)kvh + goff);
        bf16x8 alo = *(const bf16x8*)((const char*)kvl + goff);
#pragma unroll
        for (int nt = 0; nt < 4; ++nt) {
          Aacc[mt][nt] = mfma16(ahi, bq[nt], Aacc[mt][nt]);
          Aacc[mt][nt] = mfma16(alo, bq[nt], Aacc[mt][nt]);
        }
      }
    }
#pragma unroll
    for (int mt = 0; mt < 4; ++mt)
#pragma unroll
      for (int nt = 0; nt < 4; ++nt)
#pragma unroll
        for (int r = 0; r < 4; ++r) {
          float u = Aacc[mt][nt][r] * 0.03125f;
          float s = quant_step(u);
          int cv = hh * DV_ + e0 + mt * 16 + quad * 4 + r;
          int n  = w * 64 + nt * 16 + l16;
          a_s8[(tb * N_ + n) * CV_ + cv] = (unsigned char)s;
          Aacc[mt][nt][r] = __fsub_rn(Aacc[mt][nt][r], 32.0f * s);
        }
  }
}

// ---------------- Kernel 4: out = conv_bn(attn spikes/8, wp), G=2 ct-fusion -------
// R7 config: G=2, 2 blocks/CU (128 VGPR fits; (256,3) spilled in R8),
// grid 512 blocks = exactly one full scheduling round (zero tail).
__global__ __launch_bounds__(256, 2) void k4_pconv(
    const unsigned char* __restrict__ a_s8,
    const bf16_t* __restrict__ wp_hi, const bf16_t* __restrict__ wp_lo,
    const float* __restrict__ p_scale, const float* __restrict__ p_bias,
    float* __restrict__ out) {
  __shared__ __align__(16) unsigned char as_l[4][4][1024];   // 16 KB [tbi][wave][16n x 64c]
  __shared__ __align__(16) bf16_t whi_l[2][64 * 64];         // 16 KB [gi]
  __shared__ __align__(16) bf16_t wlo_l[2][64 * 64];         // 16 KB [gi]

  int ct0 = blockIdx.x * 2, ntile = blockIdx.y, tbq = blockIdx.z;
  int tid = threadIdx.x;
  int w = tid >> 6, lane = tid & 63, quad = lane >> 4, l16 = lane & 15;
  int n0b = ntile * 64;

  int r4 = lane >> 2, m4 = lane & 3;
  int sw4 = (r4 + (r4 >> 2)) & 3;
  int r8 = lane >> 3, m8 = lane & 7;

  f32x4 acc[2][4][4];                            // [gi][tbi][mt] = 128 VGPR
#pragma unroll
  for (int gi = 0; gi < 2; ++gi)
#pragma unroll
    for (int i = 0; i < 4; ++i)
#pragma unroll
      for (int mt = 0; mt < 4; ++mt) acc[gi][i][mt] = (f32x4){0.f, 0.f, 0.f, 0.f};

  for (int kc = 0; kc < 32; ++kc) {              // K = 2048, BK = 64
    int c0 = kc * 64;
    __syncthreads();
#pragma unroll
    for (int tbi = 0; tbi < 4; ++tbi) {
      const unsigned char* g = a_s8 +
          ((size_t)(tbq * 4 + tbi) * N_ + n0b + w * 16 + r4) * CV_ + c0 + ((m4 ^ sw4) << 4);
      stage16(g, &as_l[tbi][w][0], lane);
    }
#pragma unroll
    for (int gi = 0; gi < 2; ++gi) {
      const bf16_t* wrow = wp_hi + (size_t)(ct0 + gi) * 64 * CV_;
      const bf16_t* lrow = wp_lo + (size_t)(ct0 + gi) * 64 * CV_;
#pragma unroll
      for (int j = 0; j < 2; ++j) {
        int r0 = w * 16 + j * 8;
        int row = r0 + r8;
        int col = c0 + ((m8 ^ (row & 7)) << 3);
        stage16(wrow + (size_t)row * CV_ + col, (char*)&whi_l[gi][0] + r0 * 128, lane);
        stage16(lrow + (size_t)row * CV_ + col, (char*)&wlo_l[gi][0] + r0 * 128, lane);
      }
    }
    __syncthreads();
#pragma unroll
    for (int ks = 0; ks < 2; ++ks) {
      int kb = ks * 4 + quad;
      int slot = (kb >> 1) ^ ((l16 + (l16 >> 2)) & 3);
      int xoff = l16 * 64 + slot * 16 + (kb & 1) * 8;
      bf16x8 bx[4];                              // converted ONCE, used by both gi
#pragma unroll
      for (int tbi = 0; tbi < 4; ++tbi)
        bx[tbi] = cvt8(*(const u8x8*)((const char*)&as_l[tbi][w][0] + xoff));
#pragma unroll
      for (int gi = 0; gi < 2; ++gi) {
#pragma unroll
        for (int mt = 0; mt < 4; ++mt) {
          int row = mt * 16 + l16;
          int woff = row * 128 + ((kb ^ (row & 7)) << 4);
          bf16x8 ah = *(const bf16x8*)((const char*)&whi_l[gi][0] + woff);
          bf16x8 al = *(const bf16x8*)((const char*)&wlo_l[gi][0] + woff);
#pragma unroll
          for (int tbi = 0; tbi < 4; ++tbi) {
            acc[gi][tbi][mt] = mfma16(ah, bx[tbi], acc[gi][tbi][mt]);
            acc[gi][tbi][mt] = mfma16(al, bx[tbi], acc[gi][tbi][mt]);
          }
        }
      }
    }
  }
#pragma unroll
  for (int gi = 0; gi < 2; ++gi) {
    int co0 = (ct0 + gi) * 64;
#pragma unroll
    for (int mt = 0; mt < 4; ++mt)
#pragma unroll
      for (int r = 0; r < 4; ++r) {
        int c = co0 + mt * 16 + quad * 4 + r;
        float scv = __fmul_rn(p_scale[c], 0.125f);  // exact pow2 fold
        float biv = p_bias[c];
#pragma unroll
        for (int tbi = 0; tbi < 4; ++tbi) {
          float y = __fmul_rn(acc[gi][tbi][mt][r], scv);
          y = __fadd_rn(y, biv);
          int n = n0b + w * 16 + l16;
          out[((size_t)(tbq * 4 + tbi) * C_ + c) * N_ + n] = y;
        }
      }
  }
}

extern "C" void kernel_launch(void* const* d_in, const int* in_sizes, int n_in,
                              void* d_out, int out_size, void* d_ws, size_t ws_size,
                              hipStream_t stream) {
  const float* x       = (const float*)d_in[0];
  const float* wq      = (const float*)d_in[1];
  const float* wk      = (const float*)d_in[2];
  const float* wv      = (const float*)d_in[3];
  const float* wp      = (const float*)d_in[4];
  const float* q_scale = (const float*)d_in[5];
  const float* q_bias  = (const float*)d_in[6];
  const float* k_scale = (const float*)d_in[7];
  const float* k_bias  = (const float*)d_in[8];
  const float* v_scale = (const float*)d_in[9];
  const float* v_bias  = (const float*)d_in[10];
  const float* p_scale = (const float*)d_in[11];
  const float* p_bias  = (const float*)d_in[12];

  // workspace (160 MiB), time-multiplexed (R0 layout):
  //  [0,16M)   xsT u8 [T,B,N,C]       (K1 out, K2 in; dead after K2)
  //  [32,38M)  w_qkv hi|lo bf16       (k0 out, K2 in; dead after K2)
  //  [0,64M)   a_s8 [T,B,N,CV]        (K3 out, K4 in) -- clobbers the two above
  //  [64,80M)  q_s8 [T,B,N,C]         (K2 out, K3 in; dead after K3)
  //  [64,66M)+[66,68M) wp hi|lo       (k0p out after K3, K4 in)
  //  [80,96M)  k_s8 [T,B,C,N]
  //  [96,160M) v_s8 [T,B,CV,N]
  const size_t MB = 1024 * 1024;
  if (ws_size < 160 * MB) return;
  char* ws = (char*)d_ws;
  unsigned char* xsT    = (unsigned char*)(ws);
  unsigned char* a_s8   = (unsigned char*)(ws);
  bf16_t*        wqkv_h = (bf16_t*)(ws + 32 * MB);
  bf16_t*        wqkv_l = (bf16_t*)(ws + 35 * MB);
  unsigned char* q_s8   = (unsigned char*)(ws + 64 * MB);
  bf16_t*        wp_h   = (bf16_t*)(ws + 64 * MB);
  bf16_t*        wp_l   = (bf16_t*)(ws + 66 * MB);
  unsigned char* k_s8   = (unsigned char*)(ws + 80 * MB);
  unsigned char* v_s8   = (unsigned char*)(ws + 96 * MB);

  k0_split3<<<768, 256, 0, stream>>>(wq, wk, wv, wqkv_h, wqkv_l);
  k1_sfa_x<<<dim3(32, B_), 256, 0, stream>>>(x, xsT);
  k2_all<<<dim3(48, 4, B_), 256, 0, stream>>>(
      xsT, wqkv_h, wqkv_l, q_scale, q_bias, k_scale, k_bias,
      v_scale, v_bias, q_s8, k_s8, v_s8);
  k3_attn<<<dim3(4, NH_, B_), 256, 0, stream>>>(q_s8, k_s8, v_s8, a_s8);
  k0_split<<<512, 256, 0, stream>>>(wp, wp_h, wp_l, 131072);   // q_s8 dead now
  k4_pconv<<<dim3(4, 4, B_), 256, 0, stream>>>(a_s8, wp_h, wp_l,
                                               p_scale, p_bias, (float*)d_out);
}

// Round 12
// 530.300 us; speedup vs baseline: 1.0359x; 1.0359x over previous
//
#include <hip/hip_runtime.h>
#include <hip/hip_bf16.h>

#define T_  4
#define B_  32
#define C_  512
#define CV_ 2048
#define N_  256
#define NH_ 8
#define DH_ 64
#define DV_ 256

typedef __bf16 bf16_t;
typedef __bf16 bf16x8 __attribute__((ext_vector_type(8)));
typedef float  f32x4  __attribute__((ext_vector_type(4)));
typedef unsigned char u8x8 __attribute__((ext_vector_type(8)));

#if defined(__has_builtin)
# if __has_builtin(__builtin_amdgcn_global_load_lds)
#  define USE_GLL 1
# endif
#endif

__device__ __forceinline__ f32x4 mfma16(bf16x8 a, bf16x8 b, f32x4 c) {
  return __builtin_amdgcn_mfma_f32_16x16x32_bf16(a, b, c, 0, 0, 0);
}

// s = round(clip(u,0,8)); rintf = round-half-even, matching jnp.round/np.round
__device__ __forceinline__ float quant_step(float u) {
  return rintf(fminf(fmaxf(u, 0.0f), 8.0f));
}

// uchar8 (spike ints 0..8) -> bf16x8 exact integer values
__device__ __forceinline__ bf16x8 cvt8(u8x8 v) {
  bf16x8 r;
#pragma unroll
  for (int j = 0; j < 8; ++j) r[j] = (bf16_t)(float)(unsigned int)v[j];
  return r;
}

// Async 16B/lane global->LDS stage; lbase wave-uniform, HW dest = lbase+lane*16.
__device__ __forceinline__ void stage16(const void* g, void* lbase, int lane) {
#ifdef USE_GLL
  __builtin_amdgcn_global_load_lds(
      (const __attribute__((address_space(1))) void*)g,
      (__attribute__((address_space(3))) void*)lbase, 16, 0, 0);
#else
  *(uint4*)((char*)lbase + lane * 16) = *(const uint4*)g;
#endif
}

// ---------------- Kernel 0: split f32 weights into bf16 hi + lo ----------------
__global__ __launch_bounds__(256) void k0_split(const float* __restrict__ src,
                                                bf16_t* __restrict__ hi,
                                                bf16_t* __restrict__ lo, int n8) {
  int i = blockIdx.x * 256 + threadIdx.x;
  if (i >= n8) return;
  const float* s = src + (size_t)i * 8;
  bf16x8 h, l;
#pragma unroll
  for (int j = 0; j < 8; ++j) {
    float w = s[j];
    __bf16 hh = (__bf16)w;
    h[j] = hh;
    l[j] = (__bf16)(w - (float)hh);   // near-exact residual
  }
  *(bf16x8*)(hi + (size_t)i * 8) = h;
  *(bf16x8*)(lo + (size_t)i * 8) = l;
}

// k0 merged: wq(128 blk) | wk(128 blk) | wv(512 blk) in one 768-block launch.
__global__ __launch_bounds__(256) void k0_split3(
    const float* __restrict__ wq, const float* __restrict__ wk,
    const float* __restrict__ wv, bf16_t* __restrict__ hi,
    bf16_t* __restrict__ lo) {
  int bx = blockIdx.x;
  const float* src; size_t off8; int li;
  if (bx < 128)      { src = wq; off8 = 0;     li = bx; }
  else if (bx < 256) { src = wk; off8 = 32768; li = bx - 128; }
  else               { src = wv; off8 = 65536; li = bx - 256; }
  int i = li * 256 + threadIdx.x;              // exact coverage, no bounds check
  const float* s = src + (size_t)i * 8;
  bf16x8 h, l;
#pragma unroll
  for (int j = 0; j < 8; ++j) {
    float w = s[j];
    __bf16 hh = (__bf16)w;
    h[j] = hh;
    l[j] = (__bf16)(w - (float)hh);
  }
  *(bf16x8*)(hi + (off8 + (size_t)i) * 8) = h;
  *(bf16x8*)(lo + (off8 + (size_t)i) * 8) = l;
}

// ---------------- Kernel 1: xs = sfa(x) -> xsT [t,b,n,c] u8 spike ints ------------
__global__ __launch_bounds__(256) void k1_sfa_x(const float* __restrict__ x,
                                                unsigned char* __restrict__ xsT) {
  __shared__ unsigned char tile[64 * 80];        // [n][c], pad 80
  int bt = blockIdx.x;                            // c-tile = bt>>2, n-tile = bt&3
  int b  = blockIdx.y;
  int tid = threadIdx.x;
  int c0 = (bt >> 2) * 64, n0 = (bt & 3) * 64;
  int cl = tid >> 2, nc = (tid & 3) * 16;        // reader role
  int nl = tid >> 2, cj = (tid & 3) * 16;        // writer role

  float h[16];
#pragma unroll
  for (int j = 0; j < 16; ++j) h[j] = 0.0f;

  for (int t = 0; t < T_; ++t) {
    const float* xp = x + ((size_t)(t * B_ + b) * C_ + c0 + cl) * N_ + n0 + nc;
    f32x4 xv[4];
#pragma unroll
    for (int j = 0; j < 4; ++j) xv[j] = *(const f32x4*)(xp + j * 4);
    if (t) __syncthreads();
#pragma unroll
    for (int j = 0; j < 16; ++j) {
      float u = __fadd_rn(h[j], xv[j >> 2][j & 3]);  // reference scan op order
      float s = quant_step(u);
      h[j] = __fsub_rn(u, s);                    // exact
      tile[(nc + j) * 80 + cl] = (unsigned char)s;
    }
    __syncthreads();
    uint4 o = *(const uint4*)&tile[nl * 80 + cj];
    *(uint4*)(xsT + ((size_t)(t * B_ + b) * N_ + n0 + nl) * C_ + c0 + cj) = o;
  }
}

// ---------------- Kernel 2: q|k|v = sfa(conv_bn(xs, W)) ---------------------------
// R0 body (proven 155 us, pipes sum ~100% at 3 blocks/CU), merged dispatch
// (48x4x32 = 6144 blocks = 8 full scheduling rounds, zero tail). Bit-exact.
template<bool SWAPQ>
__device__ __forceinline__ void k2_body(
    const unsigned char* __restrict__ xsT,
    const bf16_t* __restrict__ w_hi, const bf16_t* __restrict__ w_lo,
    const float* __restrict__ q_scale, const float* __restrict__ q_bias,
    const float* __restrict__ k_scale, const float* __restrict__ k_bias,
    const float* __restrict__ v_scale, const float* __restrict__ v_bias,
    unsigned char* __restrict__ q_s8, unsigned char* __restrict__ k_s8,
    unsigned char* __restrict__ v_s8, int ct, int ntile, int b,
    unsigned char (*xs_l)[4][1024], bf16_t* whi_l, bf16_t* wlo_l) {
  int tid = threadIdx.x;
  int w = tid >> 6, lane = tid & 63, quad = lane >> 4, l16 = lane & 15;

  int mode, co_out;
  const float *scp, *bip;
  if (ct < 8)       { mode = 0; co_out = ct * 64;        scp = q_scale; bip = q_bias; }
  else if (ct < 16) { mode = 1; co_out = (ct - 8) * 64;  scp = k_scale; bip = k_bias; }
  else              { mode = 2; co_out = (ct - 16) * 64; scp = v_scale; bip = v_bias; }

  const bf16_t* wrow = w_hi + (size_t)ct * 64 * C_;
  const bf16_t* lrow = w_lo + (size_t)ct * 64 * C_;
  int n0b = ntile * 64;

  int r4 = lane >> 2, m4 = lane & 3;             // u8 staging roles
  int sw4 = (r4 + (r4 >> 2)) & 3;
  int r8 = lane >> 3, m8 = lane & 7;             // bf16 staging roles

  f32x4 acc[T_][4];                              // [t][mt]
#pragma unroll
  for (int t = 0; t < T_; ++t)
#pragma unroll
    for (int mt = 0; mt < 4; ++mt) acc[t][mt] = (f32x4){0.f, 0.f, 0.f, 0.f};

  for (int kc = 0; kc < 8; ++kc) {               // K = 512, BK = 64
    int c0 = kc * 64;
    __syncthreads();
    // stage xs: one instr per t (wave's own 16 n-rows)
#pragma unroll
    for (int t = 0; t < T_; ++t) {
      const unsigned char* g = xsT +
          ((size_t)(t * B_ + b) * N_ + n0b + w * 16 + r4) * C_ + c0 + ((m4 ^ sw4) << 4);
      stage16(g, &xs_l[t][w][0], lane);
    }
    // stage w hi/lo: 2+2 instr per wave
#pragma unroll
    for (int j = 0; j < 2; ++j) {
      int r0 = w * 16 + j * 8;
      int row = r0 + r8;
      int col = c0 + ((m8 ^ (row & 7)) << 3);
      stage16(wrow + (size_t)row * C_ + col, (char*)whi_l + r0 * 128, lane);
      stage16(lrow + (size_t)row * C_ + col, (char*)wlo_l + r0 * 128, lane);
    }
    __syncthreads();
#pragma unroll
    for (int ks = 0; ks < 2; ++ks) {
      int kb = ks * 4 + quad;                    // 8-elem k-granule 0..7
      int slot = (kb >> 1) ^ ((l16 + (l16 >> 2)) & 3);
      int xoff = l16 * 64 + slot * 16 + (kb & 1) * 8;
      bf16x8 bx[T_];
#pragma unroll
      for (int t = 0; t < T_; ++t)
        bx[t] = cvt8(*(const u8x8*)((const char*)&xs_l[t][w][0] + xoff));
#pragma unroll
      for (int mt = 0; mt < 4; ++mt) {
        int row = mt * 16 + l16;
        int woff = row * 128 + ((kb ^ (row & 7)) << 4);
        bf16x8 ah = *(const bf16x8*)((const char*)whi_l + woff);
        bf16x8 al = *(const bf16x8*)((const char*)wlo_l + woff);
#pragma unroll
        for (int t = 0; t < T_; ++t) {
          if (SWAPQ) {
            acc[t][mt] = mfma16(bx[t], ah, acc[t][mt]);
            acc[t][mt] = mfma16(bx[t], al, acc[t][mt]);
          } else {
            acc[t][mt] = mfma16(ah, bx[t], acc[t][mt]);
            acc[t][mt] = mfma16(al, bx[t], acc[t][mt]);
          }
        }
      }
    }
  }
  // epilogue: affine (no FMA contraction; /8 folded exactly) + t-scan + u8 store
  if (SWAPQ) {
    float sc[4], bi[4], h[4][4];
#pragma unroll
    for (int mt = 0; mt < 4; ++mt) {
      int c = co_out + mt * 16 + l16;
      sc[mt] = __fmul_rn(q_scale[c], 0.125f);    // exact pow2 fold
      bi[mt] = q_bias[c];
#pragma unroll
      for (int r = 0; r < 4; ++r) h[mt][r] = 0.0f;
    }
#pragma unroll
    for (int t = 0; t < T_; ++t)
#pragma unroll
      for (int mt = 0; mt < 4; ++mt)
#pragma unroll
        for (int r = 0; r < 4; ++r) {
          float y = __fmul_rn(acc[t][mt][r], sc[mt]);
          y = __fadd_rn(y, bi[mt]);
          float u = __fadd_rn(h[mt][r], y);
          float s = quant_step(u);
          h[mt][r] = __fsub_rn(u, s);
          int n = n0b + w * 16 + quad * 4 + r;
          int c = co_out + mt * 16 + l16;
          q_s8[((size_t)(t * B_ + b) * N_ + n) * C_ + c] = (unsigned char)s;
        }
  } else {
    float sc[4][4], bi[4][4], h[4][4];
#pragma unroll
    for (int mt = 0; mt < 4; ++mt)
#pragma unroll
      for (int r = 0; r < 4; ++r) {
        int c = co_out + mt * 16 + quad * 4 + r;
        sc[mt][r] = __fmul_rn(scp[c], 0.125f);
        bi[mt][r] = bip[c];
        h[mt][r] = 0.0f;
      }
#pragma unroll
    for (int t = 0; t < T_; ++t)
#pragma unroll
      for (int mt = 0; mt < 4; ++mt)
#pragma unroll
        for (int r = 0; r < 4; ++r) {
          float y = __fmul_rn(acc[t][mt][r], sc[mt][r]);
          y = __fadd_rn(y, bi[mt][r]);
          float u = __fadd_rn(h[mt][r], y);
          float s = quant_step(u);
          h[mt][r] = __fsub_rn(u, s);
          int n = n0b + w * 16 + l16;
          int c = co_out + mt * 16 + quad * 4 + r;
          unsigned char sp = (unsigned char)s;
          if (mode == 1) k_s8[((size_t)(t * B_ + b) * C_ + c) * N_ + n] = sp;
          else           v_s8[((size_t)(t * B_ + b) * CV_ + c) * N_ + n] = sp;
        }
  }
}

__global__ __launch_bounds__(256, 3) void k2_all(
    const unsigned char* __restrict__ xsT,
    const bf16_t* __restrict__ w_hi, const bf16_t* __restrict__ w_lo,
    const float* __restrict__ q_scale, const float* __restrict__ q_bias,
    const float* __restrict__ k_scale, const float* __restrict__ k_bias,
    const float* __restrict__ v_scale, const float* __restrict__ v_bias,
    unsigned char* __restrict__ q_s8, unsigned char* __restrict__ k_s8,
    unsigned char* __restrict__ v_s8) {
  __shared__ __align__(16) unsigned char xs_l[T_][4][1024];  // 16 KB
  __shared__ __align__(16) bf16_t whi_l[64 * 64];            //  8 KB
  __shared__ __align__(16) bf16_t wlo_l[64 * 64];            //  8 KB
  int ct = blockIdx.x, ntile = blockIdx.y, b = blockIdx.z;
  if (ct < 8)
    k2_body<true>(xsT, w_hi, w_lo, q_scale, q_bias, k_scale, k_bias,
                  v_scale, v_bias, q_s8, k_s8, v_s8, ct, ntile, b,
                  xs_l, whi_l, wlo_l);
  else
    k2_body<false>(xsT, w_hi, w_lo, q_scale, q_bias, k_scale, k_bias,
                   v_scale, v_bias, q_s8, k_s8, v_s8, ct, ntile, b,
                   xs_l, whi_l, wlo_l);
}

// ---------------- Kernel 3: attention (q·(k^T v)) + sfa, exact --------------------
// R11 structure (swapped KV, write-once hi/lo, vector A-phase reads) + NEW this
// round: the a_s8 output scatter (64 bytes over 16 cache lines per store instr,
// the worst memory pattern in the pipeline) is replaced by a wave-private LDS
// transpose: epilogue bytes go to ot[w][n][cv] (pitch 80, 16B-aligned rows),
// then 4x global_store_dwordx4 per wave per t write 16 full 64B segments per
// instruction. Same-wave LDS RAW -> no new barriers. Store values and Aacc
// residual math unchanged -> bit-exact.
__global__ __launch_bounds__(256) void k3_attn(
    const unsigned char* __restrict__ q_s8, const unsigned char* __restrict__ k_s8,
    const unsigned char* __restrict__ v_s8, unsigned char* __restrict__ a_s8) {
  __shared__ __align__(16) bf16_t kvh[64 * 64];  // [e][d] hi, XOR-swizzled, 8 KB
  __shared__ __align__(16) bf16_t kvl[64 * 64];  // [e][d] lo, 8 KB
  __shared__ __align__(16) unsigned char ot[4][64][80];  // 20 KB wave-private out tile
  int et = blockIdx.x, hh = blockIdx.y, b = blockIdx.z;
  int tid = threadIdx.x;
  int w = tid >> 6, lane = tid & 63, quad = lane >> 4, l16 = lane & 15;
  int e0 = et * 64;

  f32x4 Aacc[4][4];
#pragma unroll
  for (int mt = 0; mt < 4; ++mt)
#pragma unroll
    for (int nt = 0; nt < 4; ++nt) Aacc[mt][nt] = (f32x4){0.f, 0.f, 0.f, 0.f};

  for (int t = 0; t < T_; ++t) {
    size_t tb = (size_t)(t * B_ + b);
    f32x4 kva[4];                                // [et2]: kv[e][d] e=et2*16+quad*4+r
#pragma unroll
    for (int et2 = 0; et2 < 4; ++et2) kva[et2] = (f32x4){0.f, 0.f, 0.f, 0.f};
    const unsigned char* krow  = k_s8 + ((size_t)tb * C_ + hh * DH_ + w * 16 + l16) * N_;
    const unsigned char* vbase = v_s8 + ((size_t)tb * CV_ + hh * DV_ + e0) * N_;
    for (int kc = 0; kc < 8; ++kc) {
      int koff = kc * 32 + quad * 8;
      bf16x8 a = cvt8(*(const u8x8*)(krow + koff));
#pragma unroll
      for (int et2 = 0; et2 < 4; ++et2) {
        bf16x8 bb = cvt8(*(const u8x8*)(vbase + (size_t)(et2 * 16 + l16) * N_ + koff));
        kva[et2] = mfma16(bb, a, kva[et2]);      // SWAPPED: out row=e, col=d (exact)
      }
    }
    __syncthreads();                             // prev t's A-phase reads done
    // hi/lo convert once per element; write [e][d] with XOR-granule swizzle
#pragma unroll
    for (int et2 = 0; et2 < 4; ++et2)
#pragma unroll
      for (int r = 0; r < 4; ++r) {
        int e = et2 * 16 + quad * 4 + r;
        int d = w * 16 + l16;
        float v = kva[et2][r] * 0.015625f;       // exact pow2
        __bf16 hi = (__bf16)v;
        __bf16 lo = (__bf16)(v - (float)hi);     // exact residual (<=14 sig bits)
        int byteoff = e * 128 + ((((d >> 3) ^ (e & 7)) << 4)) + (d & 7) * 2;
        *(bf16_t*)((char*)kvh + byteoff) = hi;
        *(bf16_t*)((char*)kvl + byteoff) = lo;
      }
    __syncthreads();

    const unsigned char* qrow = q_s8 + ((size_t)tb * N_ + w * 64) * C_ + hh * DH_;
    for (int kc2 = 0; kc2 < 2; ++kc2) {
      int kbase = kc2 * 32 + quad * 8;
      bf16x8 bq[4];
#pragma unroll
      for (int nt = 0; nt < 4; ++nt)
        bq[nt] = cvt8(*(const u8x8*)(qrow + (size_t)(nt * 16 + l16) * C_ + kbase));
#pragma unroll
      for (int mt = 0; mt < 4; ++mt) {
        int e = mt * 16 + l16;
        int goff = e * 128 + (((kc2 * 4 + quad) ^ (e & 7)) << 4);
        bf16x8 ahi = *(const bf16x8*)((const char*)kvh + goff);
        bf16x8 alo = *(const bf16x8*)((const char*)kvl + goff);
#pragma unroll
        for (int nt = 0; nt < 4; ++nt) {
          Aacc[mt][nt] = mfma16(ahi, bq[nt], Aacc[mt][nt]);
          Aacc[mt][nt] = mfma16(alo, bq[nt], Aacc[mt][nt]);
        }
      }
    }
    // epilogue -> wave-private LDS transpose (bit-identical values)
#pragma unroll
    for (int mt = 0; mt < 4; ++mt)
#pragma unroll
      for (int nt = 0; nt < 4; ++nt)
#pragma unroll
        for (int r = 0; r < 4; ++r) {
          float u = Aacc[mt][nt][r] * 0.03125f;
          float s = quant_step(u);
          ot[w][nt * 16 + l16][mt * 16 + quad * 4 + r] = (unsigned char)s;
          Aacc[mt][nt][r] = __fsub_rn(Aacc[mt][nt][r], 32.0f * s);
        }
    // coalesced store: 4 passes x 16 rows x 64B (wave-private, no barrier)
    {
      int rl = lane >> 2, cb = (lane & 3) * 16;
#pragma unroll
      for (int p = 0; p < 4; ++p) {
        int j = p * 16 + rl;
        uint4 val = *(const uint4*)&ot[w][j][cb];
        int n = w * 64 + j;
        *(uint4*)(a_s8 + (tb * N_ + n) * CV_ + hh * DV_ + e0 + cb) = val;
      }
    }
  }
}

// ---------------- Kernel 4: out = conv_bn(attn spikes/8, wp), G=2 ct-fusion -------
// R7 config: G=2, 2 blocks/CU (128 VGPR fits; (256,3) spilled in R8),
// grid 512 blocks = exactly one full scheduling round (zero tail).
__global__ __launch_bounds__(256, 2) void k4_pconv(
    const unsigned char* __restrict__ a_s8,
    const bf16_t* __restrict__ wp_hi, const bf16_t* __restrict__ wp_lo,
    const float* __restrict__ p_scale, const float* __restrict__ p_bias,
    float* __restrict__ out) {
  __shared__ __align__(16) unsigned char as_l[4][4][1024];   // 16 KB [tbi][wave][16n x 64c]
  __shared__ __align__(16) bf16_t whi_l[2][64 * 64];         // 16 KB [gi]
  __shared__ __align__(16) bf16_t wlo_l[2][64 * 64];         // 16 KB [gi]

  int ct0 = blockIdx.x * 2, ntile = blockIdx.y, tbq = blockIdx.z;
  int tid = threadIdx.x;
  int w = tid >> 6, lane = tid & 63, quad = lane >> 4, l16 = lane & 15;
  int n0b = ntile * 64;

  int r4 = lane >> 2, m4 = lane & 3;
  int sw4 = (r4 + (r4 >> 2)) & 3;
  int r8 = lane >> 3, m8 = lane & 7;

  f32x4 acc[2][4][4];                            // [gi][tbi][mt] = 128 VGPR
#pragma unroll
  for (int gi = 0; gi < 2; ++gi)
#pragma unroll
    for (int i = 0; i < 4; ++i)
#pragma unroll
      for (int mt = 0; mt < 4; ++mt) acc[gi][i][mt] = (f32x4){0.f, 0.f, 0.f, 0.f};

  for (int kc = 0; kc < 32; ++kc) {              // K = 2048, BK = 64
    int c0 = kc * 64;
    __syncthreads();
#pragma unroll
    for (int tbi = 0; tbi < 4; ++tbi) {
      const unsigned char* g = a_s8 +
          ((size_t)(tbq * 4 + tbi) * N_ + n0b + w * 16 + r4) * CV_ + c0 + ((m4 ^ sw4) << 4);
      stage16(g, &as_l[tbi][w][0], lane);
    }
#pragma unroll
    for (int gi = 0; gi < 2; ++gi) {
      const bf16_t* wrow = wp_hi + (size_t)(ct0 + gi) * 64 * CV_;
      const bf16_t* lrow = wp_lo + (size_t)(ct0 + gi) * 64 * CV_;
#pragma unroll
      for (int j = 0; j < 2; ++j) {
        int r0 = w * 16 + j * 8;
        int row = r0 + r8;
        int col = c0 + ((m8 ^ (row & 7)) << 3);
        stage16(wrow + (size_t)row * CV_ + col, (char*)&whi_l[gi][0] + r0 * 128, lane);
        stage16(lrow + (size_t)row * CV_ + col, (char*)&wlo_l[gi][0] + r0 * 128, lane);
      }
    }
    __syncthreads();
#pragma unroll
    for (int ks = 0; ks < 2; ++ks) {
      int kb = ks * 4 + quad;
      int slot = (kb >> 1) ^ ((l16 + (l16 >> 2)) & 3);
      int xoff = l16 * 64 + slot * 16 + (kb & 1) * 8;
      bf16x8 bx[4];                              // converted ONCE, used by both gi
#pragma unroll
      for (int tbi = 0; tbi < 4; ++tbi)
        bx[tbi] = cvt8(*(const u8x8*)((const char*)&as_l[tbi][w][0] + xoff));
#pragma unroll
      for (int gi = 0; gi < 2; ++gi) {
#pragma unroll
        for (int mt = 0; mt < 4; ++mt) {
          int row = mt * 16 + l16;
          int woff = row * 128 + ((kb ^ (row & 7)) << 4);
          bf16x8 ah = *(const bf16x8*)((const char*)&whi_l[gi][0] + woff);
          bf16x8 al = *(const bf16x8*)((const char*)&wlo_l[gi][0] + woff);
#pragma unroll
          for (int tbi = 0; tbi < 4; ++tbi) {
            acc[gi][tbi][mt] = mfma16(ah, bx[tbi], acc[gi][tbi][mt]);
            acc[gi][tbi][mt] = mfma16(al, bx[tbi], acc[gi][tbi][mt]);
          }
        }
      }
    }
  }
#pragma unroll
  for (int gi = 0; gi < 2; ++gi) {
    int co0 = (ct0 + gi) * 64;
#pragma unroll
    for (int mt = 0; mt < 4; ++mt)
#pragma unroll
      for (int r = 0; r < 4; ++r) {
        int c = co0 + mt * 16 + quad * 4 + r;
        float scv = __fmul_rn(p_scale[c], 0.125f);  // exact pow2 fold
        float biv = p_bias[c];
#pragma unroll
        for (int tbi = 0; tbi < 4; ++tbi) {
          float y = __fmul_rn(acc[gi][tbi][mt][r], scv);
          y = __fadd_rn(y, biv);
          int n = n0b + w * 16 + l16;
          out[((size_t)(tbq * 4 + tbi) * C_ + c) * N_ + n] = y;
        }
      }
  }
}

extern "C" void kernel_launch(void* const* d_in, const int* in_sizes, int n_in,
                              void* d_out, int out_size, void* d_ws, size_t ws_size,
                              hipStream_t stream) {
  const float* x       = (const float*)d_in[0];
  const float* wq      = (const float*)d_in[1];
  const float* wk      = (const float*)d_in[2];
  const float* wv      = (const float*)d_in[3];
  const float* wp      = (const float*)d_in[4];
  const float* q_scale = (const float*)d_in[5];
  const float* q_bias  = (const float*)d_in[6];
  const float* k_scale = (const float*)d_in[7];
  const float* k_bias  = (const float*)d_in[8];
  const float* v_scale = (const float*)d_in[9];
  const float* v_bias  = (const float*)d_in[10];
  const float* p_scale = (const float*)d_in[11];
  const float* p_bias  = (const float*)d_in[12];

  // workspace (160 MiB), time-multiplexed (R0 layout):
  //  [0,16M)   xsT u8 [T,B,N,C]       (K1 out, K2 in; dead after K2)
  //  [32,38M)  w_qkv hi|lo bf16       (k0 out, K2 in; dead after K2)
  //  [0,64M)   a_s8 [T,B,N,CV]        (K3 out, K4 in) -- clobbers the two above
  //  [64,80M)  q_s8 [T,B,N,C]         (K2 out, K3 in; dead after K3)
  //  [64,66M)+[66,68M) wp hi|lo       (k0p out after K3, K4 in)
  //  [80,96M)  k_s8 [T,B,C,N]
  //  [96,160M) v_s8 [T,B,CV,N]
  const size_t MB = 1024 * 1024;
  if (ws_size < 160 * MB) return;
  char* ws = (char*)d_ws;
  unsigned char* xsT    = (unsigned char*)(ws);
  unsigned char* a_s8   = (unsigned char*)(ws);
  bf16_t*        wqkv_h = (bf16_t*)(ws + 32 * MB);
  bf16_t*        wqkv_l = (bf16_t*)(ws + 35 * MB);
  unsigned char* q_s8   = (unsigned char*)(ws + 64 * MB);
  bf16_t*        wp_h   = (bf16_t*)(ws + 64 * MB);
  bf16_t*        wp_l   = (bf16_t*)(ws + 66 * MB);
  unsigned char* k_s8   = (unsigned char*)(ws + 80 * MB);
  unsigned char* v_s8   = (unsigned char*)(ws + 96 * MB);

  k0_split3<<<768, 256, 0, stream>>>(wq, wk, wv, wqkv_h, wqkv_l);
  k1_sfa_x<<<dim3(32, B_), 256, 0, stream>>>(x, xsT);
  k2_all<<<dim3(48, 4, B_), 256, 0, stream>>>(
      xsT, wqkv_h, wqkv_l, q_scale, q_bias, k_scale, k_bias,
      v_scale, v_bias, q_s8, k_s8, v_s8);
  k3_attn<<<dim3(4, NH_, B_), 256, 0, stream>>>(q_s8, k_s8, v_s8, a_s8);
  k0_split<<<512, 256, 0, stream>>>(wp, wp_h, wp_l, 131072);   // q_s8 dead now
  k4_pconv<<<dim3(4, 4, B_), 256, 0, stream>>>(a_s8, wp_h, wp_l,
                                               p_scale, p_bias, (float*)d_out);
}

// Round 13
// 498.966 us; speedup vs baseline: 1.1010x; 1.0628x over previous
//
#include <hip/hip_runtime.h>
#include <hip/hip_bf16.h>

#define T_  4
#define B_  32
#define C_  512
#define CV_ 2048
#define N_  256
#define NH_ 8
#define DH_ 64
#define DV_ 256

typedef __bf16 bf16_t;
typedef __bf16 bf16x8 __attribute__((ext_vector_type(8)));
typedef float  f32x4  __attribute__((ext_vector_type(4)));
typedef int    i32x4  __attribute__((ext_vector_type(4)));
typedef unsigned char u8x8 __attribute__((ext_vector_type(8)));

#if defined(__has_builtin)
# if __has_builtin(__builtin_amdgcn_global_load_lds)
#  define USE_GLL 1
# endif
#endif

__device__ __forceinline__ f32x4 mfma16(bf16x8 a, bf16x8 b, f32x4 c) {
  return __builtin_amdgcn_mfma_f32_16x16x32_bf16(a, b, c, 0, 0, 0);
}

// i8 MFMA K=64: exact integer dot product (spikes 0..8, |acc| <= 2^14)
__device__ __forceinline__ i32x4 mfma_i8(i32x4 a, i32x4 b, i32x4 c) {
  return __builtin_amdgcn_mfma_i32_16x16x64_i8(a, b, c, 0, 0, 0);
}

// s = round(clip(u,0,8)); rintf = round-half-even, matching jnp.round/np.round
__device__ __forceinline__ float quant_step(float u) {
  return rintf(fminf(fmaxf(u, 0.0f), 8.0f));
}

// uchar8 (spike ints 0..8) -> bf16x8 exact integer values
__device__ __forceinline__ bf16x8 cvt8(u8x8 v) {
  bf16x8 r;
#pragma unroll
  for (int j = 0; j < 8; ++j) r[j] = (bf16_t)(float)(unsigned int)v[j];
  return r;
}

// Async 16B/lane global->LDS stage; lbase wave-uniform, HW dest = lbase+lane*16.
__device__ __forceinline__ void stage16(const void* g, void* lbase, int lane) {
#ifdef USE_GLL
  __builtin_amdgcn_global_load_lds(
      (const __attribute__((address_space(1))) void*)g,
      (__attribute__((address_space(3))) void*)lbase, 16, 0, 0);
#else
  *(uint4*)((char*)lbase + lane * 16) = *(const uint4*)g;
#endif
}

// ---------------- Kernel 0: split f32 weights into bf16 hi + lo ----------------
__global__ __launch_bounds__(256) void k0_split(const float* __restrict__ src,
                                                bf16_t* __restrict__ hi,
                                                bf16_t* __restrict__ lo, int n8) {
  int i = blockIdx.x * 256 + threadIdx.x;
  if (i >= n8) return;
  const float* s = src + (size_t)i * 8;
  bf16x8 h, l;
#pragma unroll
  for (int j = 0; j < 8; ++j) {
    float w = s[j];
    __bf16 hh = (__bf16)w;
    h[j] = hh;
    l[j] = (__bf16)(w - (float)hh);   // near-exact residual
  }
  *(bf16x8*)(hi + (size_t)i * 8) = h;
  *(bf16x8*)(lo + (size_t)i * 8) = l;
}

// k0 merged: wq(128 blk) | wk(128 blk) | wv(512 blk) in one 768-block launch.
__global__ __launch_bounds__(256) void k0_split3(
    const float* __restrict__ wq, const float* __restrict__ wk,
    const float* __restrict__ wv, bf16_t* __restrict__ hi,
    bf16_t* __restrict__ lo) {
  int bx = blockIdx.x;
  const float* src; size_t off8; int li;
  if (bx < 128)      { src = wq; off8 = 0;     li = bx; }
  else if (bx < 256) { src = wk; off8 = 32768; li = bx - 128; }
  else               { src = wv; off8 = 65536; li = bx - 256; }
  int i = li * 256 + threadIdx.x;              // exact coverage, no bounds check
  const float* s = src + (size_t)i * 8;
  bf16x8 h, l;
#pragma unroll
  for (int j = 0; j < 8; ++j) {
    float w = s[j];
    __bf16 hh = (__bf16)w;
    h[j] = hh;
    l[j] = (__bf16)(w - (float)hh);
  }
  *(bf16x8*)(hi + (off8 + (size_t)i) * 8) = h;
  *(bf16x8*)(lo + (off8 + (size_t)i) * 8) = l;
}

// ---------------- Kernel 1: xs = sfa(x) -> xsT [t,b,n,c] u8 spike ints ------------
__global__ __launch_bounds__(256) void k1_sfa_x(const float* __restrict__ x,
                                                unsigned char* __restrict__ xsT) {
  __shared__ unsigned char tile[64 * 80];        // [n][c], pad 80
  int bt = blockIdx.x;                            // c-tile = bt>>2, n-tile = bt&3
  int b  = blockIdx.y;
  int tid = threadIdx.x;
  int c0 = (bt >> 2) * 64, n0 = (bt & 3) * 64;
  int cl = tid >> 2, nc = (tid & 3) * 16;        // reader role
  int nl = tid >> 2, cj = (tid & 3) * 16;        // writer role

  float h[16];
#pragma unroll
  for (int j = 0; j < 16; ++j) h[j] = 0.0f;

  for (int t = 0; t < T_; ++t) {
    const float* xp = x + ((size_t)(t * B_ + b) * C_ + c0 + cl) * N_ + n0 + nc;
    f32x4 xv[4];
#pragma unroll
    for (int j = 0; j < 4; ++j) xv[j] = *(const f32x4*)(xp + j * 4);
    if (t) __syncthreads();
#pragma unroll
    for (int j = 0; j < 16; ++j) {
      float u = __fadd_rn(h[j], xv[j >> 2][j & 3]);  // reference scan op order
      float s = quant_step(u);
      h[j] = __fsub_rn(u, s);                    // exact
      tile[(nc + j) * 80 + cl] = (unsigned char)s;
    }
    __syncthreads();
    uint4 o = *(const uint4*)&tile[nl * 80 + cj];
    *(uint4*)(xsT + ((size_t)(t * B_ + b) * N_ + n0 + nl) * C_ + c0 + cj) = o;
  }
}

// ---------------- Kernel 2: q|k|v = sfa(conv_bn(xs, W)) ---------------------------
// R0 body (proven 155 us, pipes sum ~100% at 3 blocks/CU), merged dispatch
// (48x4x32 = 6144 blocks = 8 full scheduling rounds, zero tail). Bit-exact.
template<bool SWAPQ>
__device__ __forceinline__ void k2_body(
    const unsigned char* __restrict__ xsT,
    const bf16_t* __restrict__ w_hi, const bf16_t* __restrict__ w_lo,
    const float* __restrict__ q_scale, const float* __restrict__ q_bias,
    const float* __restrict__ k_scale, const float* __restrict__ k_bias,
    const float* __restrict__ v_scale, const float* __restrict__ v_bias,
    unsigned char* __restrict__ q_s8, unsigned char* __restrict__ k_s8,
    unsigned char* __restrict__ v_s8, int ct, int ntile, int b,
    unsigned char (*xs_l)[4][1024], bf16_t* whi_l, bf16_t* wlo_l) {
  int tid = threadIdx.x;
  int w = tid >> 6, lane = tid & 63, quad = lane >> 4, l16 = lane & 15;

  int mode, co_out;
  const float *scp, *bip;
  if (ct < 8)       { mode = 0; co_out = ct * 64;        scp = q_scale; bip = q_bias; }
  else if (ct < 16) { mode = 1; co_out = (ct - 8) * 64;  scp = k_scale; bip = k_bias; }
  else              { mode = 2; co_out = (ct - 16) * 64; scp = v_scale; bip = v_bias; }

  const bf16_t* wrow = w_hi + (size_t)ct * 64 * C_;
  const bf16_t* lrow = w_lo + (size_t)ct * 64 * C_;
  int n0b = ntile * 64;

  int r4 = lane >> 2, m4 = lane & 3;             // u8 staging roles
  int sw4 = (r4 + (r4 >> 2)) & 3;
  int r8 = lane >> 3, m8 = lane & 7;             // bf16 staging roles

  f32x4 acc[T_][4];                              // [t][mt]
#pragma unroll
  for (int t = 0; t < T_; ++t)
#pragma unroll
    for (int mt = 0; mt < 4; ++mt) acc[t][mt] = (f32x4){0.f, 0.f, 0.f, 0.f};

  for (int kc = 0; kc < 8; ++kc) {               // K = 512, BK = 64
    int c0 = kc * 64;
    __syncthreads();
    // stage xs: one instr per t (wave's own 16 n-rows)
#pragma unroll
    for (int t = 0; t < T_; ++t) {
      const unsigned char* g = xsT +
          ((size_t)(t * B_ + b) * N_ + n0b + w * 16 + r4) * C_ + c0 + ((m4 ^ sw4) << 4);
      stage16(g, &xs_l[t][w][0], lane);
    }
    // stage w hi/lo: 2+2 instr per wave
#pragma unroll
    for (int j = 0; j < 2; ++j) {
      int r0 = w * 16 + j * 8;
      int row = r0 + r8;
      int col = c0 + ((m8 ^ (row & 7)) << 3);
      stage16(wrow + (size_t)row * C_ + col, (char*)whi_l + r0 * 128, lane);
      stage16(lrow + (size_t)row * C_ + col, (char*)wlo_l + r0 * 128, lane);
    }
    __syncthreads();
#pragma unroll
    for (int ks = 0; ks < 2; ++ks) {
      int kb = ks * 4 + quad;                    // 8-elem k-granule 0..7
      int slot = (kb >> 1) ^ ((l16 + (l16 >> 2)) & 3);
      int xoff = l16 * 64 + slot * 16 + (kb & 1) * 8;
      bf16x8 bx[T_];
#pragma unroll
      for (int t = 0; t < T_; ++t)
        bx[t] = cvt8(*(const u8x8*)((const char*)&xs_l[t][w][0] + xoff));
#pragma unroll
      for (int mt = 0; mt < 4; ++mt) {
        int row = mt * 16 + l16;
        int woff = row * 128 + ((kb ^ (row & 7)) << 4);
        bf16x8 ah = *(const bf16x8*)((const char*)whi_l + woff);
        bf16x8 al = *(const bf16x8*)((const char*)wlo_l + woff);
#pragma unroll
        for (int t = 0; t < T_; ++t) {
          if (SWAPQ) {
            acc[t][mt] = mfma16(bx[t], ah, acc[t][mt]);
            acc[t][mt] = mfma16(bx[t], al, acc[t][mt]);
          } else {
            acc[t][mt] = mfma16(ah, bx[t], acc[t][mt]);
            acc[t][mt] = mfma16(al, bx[t], acc[t][mt]);
          }
        }
      }
    }
  }
  // epilogue: affine (no FMA contraction; /8 folded exactly) + t-scan + u8 store
  if (SWAPQ) {
    float sc[4], bi[4], h[4][4];
#pragma unroll
    for (int mt = 0; mt < 4; ++mt) {
      int c = co_out + mt * 16 + l16;
      sc[mt] = __fmul_rn(q_scale[c], 0.125f);    // exact pow2 fold
      bi[mt] = q_bias[c];
#pragma unroll
      for (int r = 0; r < 4; ++r) h[mt][r] = 0.0f;
    }
#pragma unroll
    for (int t = 0; t < T_; ++t)
#pragma unroll
      for (int mt = 0; mt < 4; ++mt)
#pragma unroll
        for (int r = 0; r < 4; ++r) {
          float y = __fmul_rn(acc[t][mt][r], sc[mt]);
          y = __fadd_rn(y, bi[mt]);
          float u = __fadd_rn(h[mt][r], y);
          float s = quant_step(u);
          h[mt][r] = __fsub_rn(u, s);
          int n = n0b + w * 16 + quad * 4 + r;
          int c = co_out + mt * 16 + l16;
          q_s8[((size_t)(t * B_ + b) * N_ + n) * C_ + c] = (unsigned char)s;
        }
  } else {
    float sc[4][4], bi[4][4], h[4][4];
#pragma unroll
    for (int mt = 0; mt < 4; ++mt)
#pragma unroll
      for (int r = 0; r < 4; ++r) {
        int c = co_out + mt * 16 + quad * 4 + r;
        sc[mt][r] = __fmul_rn(scp[c], 0.125f);
        bi[mt][r] = bip[c];
        h[mt][r] = 0.0f;
      }
#pragma unroll
    for (int t = 0; t < T_; ++t)
#pragma unroll
      for (int mt = 0; mt < 4; ++mt)
#pragma unroll
        for (int r = 0; r < 4; ++r) {
          float y = __fmul_rn(acc[t][mt][r], sc[mt][r]);
          y = __fadd_rn(y, bi[mt][r]);
          float u = __fadd_rn(h[mt][r], y);
          float s = quant_step(u);
          h[mt][r] = __fsub_rn(u, s);
          int n = n0b + w * 16 + l16;
          int c = co_out + mt * 16 + quad * 4 + r;
          unsigned char sp = (unsigned char)s;
          if (mode == 1) k_s8[((size_t)(t * B_ + b) * C_ + c) * N_ + n] = sp;
          else           v_s8[((size_t)(t * B_ + b) * CV_ + c) * N_ + n] = sp;
        }
  }
}

__global__ __launch_bounds__(256, 3) void k2_all(
    const unsigned char* __restrict__ xsT,
    const bf16_t* __restrict__ w_hi, const bf16_t* __restrict__ w_lo,
    const float* __restrict__ q_scale, const float* __restrict__ q_bias,
    const float* __restrict__ k_scale, const float* __restrict__ k_bias,
    const float* __restrict__ v_scale, const float* __restrict__ v_bias,
    unsigned char* __restrict__ q_s8, unsigned char* __restrict__ k_s8,
    unsigned char* __restrict__ v_s8) {
  __shared__ __align__(16) unsigned char xs_l[T_][4][1024];  // 16 KB
  __shared__ __align__(16) bf16_t whi_l[64 * 64];            //  8 KB
  __shared__ __align__(16) bf16_t wlo_l[64 * 64];            //  8 KB
  int ct = blockIdx.x, ntile = blockIdx.y, b = blockIdx.z;
  if (ct < 8)
    k2_body<true>(xsT, w_hi, w_lo, q_scale, q_bias, k_scale, k_bias,
                  v_scale, v_bias, q_s8, k_s8, v_s8, ct, ntile, b,
                  xs_l, whi_l, wlo_l);
  else
    k2_body<false>(xsT, w_hi, w_lo, q_scale, q_bias, k_scale, k_bias,
                   v_scale, v_bias, q_s8, k_s8, v_s8, ct, ntile, b,
                   xs_l, whi_l, wlo_l);
}

// ---------------- Kernel 3: attention (q·(k^T v)) + sfa, exact --------------------
// R12 structure + NEW: KV phase via mfma_i32_16x16x64_i8. Both KV operands are
// spike ints 0..8 (u8), so k^T·v is EXACT in i32 (max 2^14): zero conversion
// VALU (was 40 cvt8 ~ 480 VALU/lane/t), 16B contiguous loads (was 8B scattered),
// 16 MFMA/t (was 32). i32 sum order-invariant = old exact-f32 sum -> the
// i32->f32->hi/lo conversion yields bit-identical A-phase operands. Any internal
// K-permutation of the i8 layout cancels (A and B fed with the same n-mapping).
__global__ __launch_bounds__(256) void k3_attn(
    const unsigned char* __restrict__ q_s8, const unsigned char* __restrict__ k_s8,
    const unsigned char* __restrict__ v_s8, unsigned char* __restrict__ a_s8) {
  __shared__ __align__(16) bf16_t kvh[64 * 64];  // [e][d] hi, XOR-swizzled, 8 KB
  __shared__ __align__(16) bf16_t kvl[64 * 64];  // [e][d] lo, 8 KB
  __shared__ __align__(16) unsigned char ot[4][64][80];  // 20 KB wave-private out tile
  int et = blockIdx.x, hh = blockIdx.y, b = blockIdx.z;
  int tid = threadIdx.x;
  int w = tid >> 6, lane = tid & 63, quad = lane >> 4, l16 = lane & 15;
  int e0 = et * 64;

  f32x4 Aacc[4][4];
#pragma unroll
  for (int mt = 0; mt < 4; ++mt)
#pragma unroll
    for (int nt = 0; nt < 4; ++nt) Aacc[mt][nt] = (f32x4){0.f, 0.f, 0.f, 0.f};

  for (int t = 0; t < T_; ++t) {
    size_t tb = (size_t)(t * B_ + b);
    i32x4 kva[4];                                // [et2]: kv[e][d], exact i32
#pragma unroll
    for (int et2 = 0; et2 < 4; ++et2) kva[et2] = (i32x4){0, 0, 0, 0};
    const unsigned char* krow  = k_s8 + ((size_t)tb * C_ + hh * DH_ + w * 16 + l16) * N_;
    const unsigned char* vbase = v_s8 + ((size_t)tb * CV_ + hh * DV_ + e0) * N_;
#pragma unroll
    for (int kc = 0; kc < 4; ++kc) {             // K=256 over n, 64 per MFMA
      int koff = kc * 64 + quad * 16;
      i32x4 bk = *(const i32x4*)(krow + koff);   // k[d=w*16+l16][n-chunk], 16B
#pragma unroll
      for (int et2 = 0; et2 < 4; ++et2) {
        i32x4 av = *(const i32x4*)(vbase + (size_t)(et2 * 16 + l16) * N_ + koff);
        kva[et2] = mfma_i8(av, bk, kva[et2]);    // A=v rows e, B=k cols d
      }
    }
    __syncthreads();                             // prev t's A-phase reads done
    // hi/lo convert once per element; write [e][d] with XOR-granule swizzle
#pragma unroll
    for (int et2 = 0; et2 < 4; ++et2)
#pragma unroll
      for (int r = 0; r < 4; ++r) {
        int e = et2 * 16 + quad * 4 + r;
        int d = w * 16 + l16;
        float v = (float)kva[et2][r] * 0.015625f; // exact (|kv| <= 2^14), pow2
        __bf16 hi = (__bf16)v;
        __bf16 lo = (__bf16)(v - (float)hi);     // exact residual (<=14 sig bits)
        int byteoff = e * 128 + ((((d >> 3) ^ (e & 7)) << 4)) + (d & 7) * 2;
        *(bf16_t*)((char*)kvh + byteoff) = hi;
        *(bf16_t*)((char*)kvl + byteoff) = lo;
      }
    __syncthreads();

    const unsigned char* qrow = q_s8 + ((size_t)tb * N_ + w * 64) * C_ + hh * DH_;
    for (int kc2 = 0; kc2 < 2; ++kc2) {
      int kbase = kc2 * 32 + quad * 8;
      bf16x8 bq[4];
#pragma unroll
      for (int nt = 0; nt < 4; ++nt)
        bq[nt] = cvt8(*(const u8x8*)(qrow + (size_t)(nt * 16 + l16) * C_ + kbase));
#pragma unroll
      for (int mt = 0; mt < 4; ++mt) {
        int e = mt * 16 + l16;
        int goff = e * 128 + (((kc2 * 4 + quad) ^ (e & 7)) << 4);
        bf16x8 ahi = *(const bf16x8*)((const char*)kvh + goff);
        bf16x8 alo = *(const bf16x8*)((const char*)kvl + goff);
#pragma unroll
        for (int nt = 0; nt < 4; ++nt) {
          Aacc[mt][nt] = mfma16(ahi, bq[nt], Aacc[mt][nt]);
          Aacc[mt][nt] = mfma16(alo, bq[nt], Aacc[mt][nt]);
        }
      }
    }
    // epilogue -> wave-private LDS transpose (bit-identical values)
#pragma unroll
    for (int mt = 0; mt < 4; ++mt)
#pragma unroll
      for (int nt = 0; nt < 4; ++nt)
#pragma unroll
        for (int r = 0; r < 4; ++r) {
          float u = Aacc[mt][nt][r] * 0.03125f;
          float s = quant_step(u);
          ot[w][nt * 16 + l16][mt * 16 + quad * 4 + r] = (unsigned char)s;
          Aacc[mt][nt][r] = __fsub_rn(Aacc[mt][nt][r], 32.0f * s);
        }
    // coalesced store: 4 passes x 16 rows x 64B (wave-private, no barrier)
    {
      int rl = lane >> 2, cb = (lane & 3) * 16;
#pragma unroll
      for (int p = 0; p < 4; ++p) {
        int j = p * 16 + rl;
        uint4 val = *(const uint4*)&ot[w][j][cb];
        int n = w * 64 + j;
        *(uint4*)(a_s8 + (tb * N_ + n) * CV_ + hh * DV_ + e0 + cb) = val;
      }
    }
  }
}

// ---------------- Kernel 4: out = conv_bn(attn spikes/8, wp), G=2 ct-fusion -------
// R7 config: G=2, 2 blocks/CU (128 VGPR fits; (256,3) spilled in R8),
// grid 512 blocks = exactly one full scheduling round (zero tail).
__global__ __launch_bounds__(256, 2) void k4_pconv(
    const unsigned char* __restrict__ a_s8,
    const bf16_t* __restrict__ wp_hi, const bf16_t* __restrict__ wp_lo,
    const float* __restrict__ p_scale, const float* __restrict__ p_bias,
    float* __restrict__ out) {
  __shared__ __align__(16) unsigned char as_l[4][4][1024];   // 16 KB [tbi][wave][16n x 64c]
  __shared__ __align__(16) bf16_t whi_l[2][64 * 64];         // 16 KB [gi]
  __shared__ __align__(16) bf16_t wlo_l[2][64 * 64];         // 16 KB [gi]

  int ct0 = blockIdx.x * 2, ntile = blockIdx.y, tbq = blockIdx.z;
  int tid = threadIdx.x;
  int w = tid >> 6, lane = tid & 63, quad = lane >> 4, l16 = lane & 15;
  int n0b = ntile * 64;

  int r4 = lane >> 2, m4 = lane & 3;
  int sw4 = (r4 + (r4 >> 2)) & 3;
  int r8 = lane >> 3, m8 = lane & 7;

  f32x4 acc[2][4][4];                            // [gi][tbi][mt] = 128 VGPR
#pragma unroll
  for (int gi = 0; gi < 2; ++gi)
#pragma unroll
    for (int i = 0; i < 4; ++i)
#pragma unroll
      for (int mt = 0; mt < 4; ++mt) acc[gi][i][mt] = (f32x4){0.f, 0.f, 0.f, 0.f};

  for (int kc = 0; kc < 32; ++kc) {              // K = 2048, BK = 64
    int c0 = kc * 64;
    __syncthreads();
#pragma unroll
    for (int tbi = 0; tbi < 4; ++tbi) {
      const unsigned char* g = a_s8 +
          ((size_t)(tbq * 4 + tbi) * N_ + n0b + w * 16 + r4) * CV_ + c0 + ((m4 ^ sw4) << 4);
      stage16(g, &as_l[tbi][w][0], lane);
    }
#pragma unroll
    for (int gi = 0; gi < 2; ++gi) {
      const bf16_t* wrow = wp_hi + (size_t)(ct0 + gi) * 64 * CV_;
      const bf16_t* lrow = wp_lo + (size_t)(ct0 + gi) * 64 * CV_;
#pragma unroll
      for (int j = 0; j < 2; ++j) {
        int r0 = w * 16 + j * 8;
        int row = r0 + r8;
        int col = c0 + ((m8 ^ (row & 7)) << 3);
        stage16(wrow + (size_t)row * CV_ + col, (char*)&whi_l[gi][0] + r0 * 128, lane);
        stage16(lrow + (size_t)row * CV_ + col, (char*)&wlo_l[gi][0] + r0 * 128, lane);
      }
    }
    __syncthreads();
#pragma unroll
    for (int ks = 0; ks < 2; ++ks) {
      int kb = ks * 4 + quad;
      int slot = (kb >> 1) ^ ((l16 + (l16 >> 2)) & 3);
      int xoff = l16 * 64 + slot * 16 + (kb & 1) * 8;
      bf16x8 bx[4];                              // converted ONCE, used by both gi
#pragma unroll
      for (int tbi = 0; tbi < 4; ++tbi)
        bx[tbi] = cvt8(*(const u8x8*)((const char*)&as_l[tbi][w][0] + xoff));
#pragma unroll
      for (int gi = 0; gi < 2; ++gi) {
#pragma unroll
        for (int mt = 0; mt < 4; ++mt) {
          int row = mt * 16 + l16;
          int woff = row * 128 + ((kb ^ (row & 7)) << 4);
          bf16x8 ah = *(const bf16x8*)((const char*)&whi_l[gi][0] + woff);
          bf16x8 al = *(const bf16x8*)((const char*)&wlo_l[gi][0] + woff);
#pragma unroll
          for (int tbi = 0; tbi < 4; ++tbi) {
            acc[gi][tbi][mt] = mfma16(ah, bx[tbi], acc[gi][tbi][mt]);
            acc[gi][tbi][mt] = mfma16(al, bx[tbi], acc[gi][tbi][mt]);
          }
        }
      }
    }
  }
#pragma unroll
  for (int gi = 0; gi < 2; ++gi) {
    int co0 = (ct0 + gi) * 64;
#pragma unroll
    for (int mt = 0; mt < 4; ++mt)
#pragma unroll
      for (int r = 0; r < 4; ++r) {
        int c = co0 + mt * 16 + quad * 4 + r;
        float scv = __fmul_rn(p_scale[c], 0.125f);  // exact pow2 fold
        float biv = p_bias[c];
#pragma unroll
        for (int tbi = 0; tbi < 4; ++tbi) {
          float y = __fmul_rn(acc[gi][tbi][mt][r], scv);
          y = __fadd_rn(y, biv);
          int n = n0b + w * 16 + l16;
          out[((size_t)(tbq * 4 + tbi) * C_ + c) * N_ + n] = y;
        }
      }
  }
}

extern "C" void kernel_launch(void* const* d_in, const int* in_sizes, int n_in,
                              void* d_out, int out_size, void* d_ws, size_t ws_size,
                              hipStream_t stream) {
  const float* x       = (const float*)d_in[0];
  const float* wq      = (const float*)d_in[1];
  const float* wk      = (const float*)d_in[2];
  const float* wv      = (const float*)d_in[3];
  const float* wp      = (const float*)d_in[4];
  const float* q_scale = (const float*)d_in[5];
  const float* q_bias  = (const float*)d_in[6];
  const float* k_scale = (const float*)d_in[7];
  const float* k_bias  = (const float*)d_in[8];
  const float* v_scale = (const float*)d_in[9];
  const float* v_bias  = (const float*)d_in[10];
  const float* p_scale = (const float*)d_in[11];
  const float* p_bias  = (const float*)d_in[12];

  // workspace (160 MiB), time-multiplexed (R0 layout):
  //  [0,16M)   xsT u8 [T,B,N,C]       (K1 out, K2 in; dead after K2)
  //  [32,38M)  w_qkv hi|lo bf16       (k0 out, K2 in; dead after K2)
  //  [0,64M)   a_s8 [T,B,N,CV]        (K3 out, K4 in) -- clobbers the two above
  //  [64,80M)  q_s8 [T,B,N,C]         (K2 out, K3 in; dead after K3)
  //  [64,66M)+[66,68M) wp hi|lo       (k0p out after K3, K4 in)
  //  [80,96M)  k_s8 [T,B,C,N]
  //  [96,160M) v_s8 [T,B,CV,N]
  const size_t MB = 1024 * 1024;
  if (ws_size < 160 * MB) return;
  char* ws = (char*)d_ws;
  unsigned char* xsT    = (unsigned char*)(ws);
  unsigned char* a_s8   = (unsigned char*)(ws);
  bf16_t*        wqkv_h = (bf16_t*)(ws + 32 * MB);
  bf16_t*        wqkv_l = (bf16_t*)(ws + 35 * MB);
  unsigned char* q_s8   = (unsigned char*)(ws + 64 * MB);
  bf16_t*        wp_h   = (bf16_t*)(ws + 64 * MB);
  bf16_t*        wp_l   = (bf16_t*)(ws + 66 * MB);
  unsigned char* k_s8   = (unsigned char*)(ws + 80 * MB);
  unsigned char* v_s8   = (unsigned char*)(ws + 96 * MB);

  k0_split3<<<768, 256, 0, stream>>>(wq, wk, wv, wqkv_h, wqkv_l);
  k1_sfa_x<<<dim3(32, B_), 256, 0, stream>>>(x, xsT);
  k2_all<<<dim3(48, 4, B_), 256, 0, stream>>>(
      xsT, wqkv_h, wqkv_l, q_scale, q_bias, k_scale, k_bias,
      v_scale, v_bias, q_s8, k_s8, v_s8);
  k3_attn<<<dim3(4, NH_, B_), 256, 0, stream>>>(q_s8, k_s8, v_s8, a_s8);
  k0_split<<<512, 256, 0, stream>>>(wp, wp_h, wp_l, 131072);   // q_s8 dead now
  k4_pconv<<<dim3(4, 4, B_), 256, 0, stream>>>(a_s8, wp_h, wp_l,
                                               p_scale, p_bias, (float*)d_out);
}